// Round 2
// baseline (1485.465 us; speedup 1.0000x reference)
//
#include <hip/hip_runtime.h>
#include <float.h>

// MAM dense, fused. C[m,n] = max_k(A[m,k]*W[n,k]) + min_k + bias[n] + arg
// indices (numpy first-occurrence).
//
// R2 theory: kernel is LDS-pipe-bound (per CU/chunk: 6144 LDS cyc vs 4600
// VALU cyc/SIMD at R0's 4x4 tile). Changes vs R0/R1:
//  - 8x4/thread tile (BM=128, BN=64): 6 ds_read_b128 per k-pair for 64
//    products (vs 4 per 32) -> main-pass LDS read cycles x0.75.
//  - NO tgt array: rescan recomputes the in-chunk max/argmax directly
//    (ascending k, strict > = first occurrence). The tracked chunk contains
//    the global max, so its in-chunk max IS the global max — no bitwise
//    target compare needed. Min side via sign-flipped W (exact: a*(-w) =
//    -(a*w) bitwise). Kills 32KB LDS + R1's global-parking traffic blowup
//    (R1: WRITE_SIZE 1.27GB from scattered scalar round-trips — reverted).
//  - pk_mul (VOP3P packed fp32, op_sel broadcast) kept: VALU issue slack.
//  - XOR-swizzled transpose staging + global->reg prefetch pipeline kept.
//  - cmax/cmin packed into one u32 (8 bits each) to hold VGPR <= 256.
// LDS: pool 27648 (main 25600 aliased w/ rescan 27648) + ents 32768 = ~60.7KB
// -> 2 blocks/CU.

typedef float f32x2 __attribute__((ext_vector_type(2)));
typedef float f32x4 __attribute__((ext_vector_type(4)));

#define BM 128
#define BN 64
#define BK 32
#define LDPA 132  // main A staging [BK][132] (transpose, +4 pad)
#define LDPW 68   // main W staging [BK][68]
#define LDP2 36   // rescan row-major [rows][36]; 144B stride
#define NCHUNK 32
#define NENT (BM * BN * 2)  // 16384
#define POOLSZ 27648        // max(main 25600, rescan 27648)

// D.lo = S0.lo * S1.lo ; D.hi = S0.hi * S1.lo   (broadcast S1 low half)
__device__ __forceinline__ f32x2 pk_mul_blo(f32x2 a, f32x2 w) {
  f32x2 d;
  asm("v_pk_mul_f32 %0, %1, %2 op_sel:[0,0] op_sel_hi:[1,0]"
      : "=v"(d) : "v"(a), "v"(w));
  return d;
}
// D.lo = S0.lo * S1.hi ; D.hi = S0.hi * S1.hi   (broadcast S1 high half)
__device__ __forceinline__ f32x2 pk_mul_bhi(f32x2 a, f32x2 w) {
  f32x2 d;
  asm("v_pk_mul_f32 %0, %1, %2 op_sel:[0,1] op_sel_hi:[1,1]"
      : "=v"(d) : "v"(a), "v"(w));
  return d;
}

__global__ __launch_bounds__(256, 2)
void mam_fused(const float* __restrict__ A, const float* __restrict__ W,
               const float* __restrict__ bias,
               float* __restrict__ out_v, float* __restrict__ out_ax,
               float* __restrict__ out_an, int M, int N, int K) {
  __shared__ __align__(16) unsigned char pool[POOLSZ];
  float(*Als)[LDPA] = (float(*)[LDPA])pool;                 // 32x132 = 16896B
  float(*Wls)[LDPW] = (float(*)[LDPW])(pool + 16896);       // 32x68  =  8704B
  float(*As2)[LDP2] = (float(*)[LDP2])pool;                 // 128x36 = 18432B
  float(*Ws2)[LDP2] = (float(*)[LDP2])(pool + 18432);       // 64x36  =  9216B
  __shared__ unsigned short ents[NENT];
  __shared__ unsigned cnt[NCHUNK];
  __shared__ unsigned off[NCHUNK + 1];

  const int tid = threadIdx.x;
  const int tx = tid & 15;   // n: 4 cols each
  const int ty = tid >> 4;   // m: 8 rows each (0..15)
  const int m0 = blockIdx.y * BM;
  const int n0 = blockIdx.x * BN;

  float vmax[8][4], vmin[8][4];
  unsigned cpk[8][4];  // cmax | (cmin<<8)
#pragma unroll
  for (int i = 0; i < 8; ++i)
#pragma unroll
    for (int j = 0; j < 4; ++j) {
      vmax[i][j] = -FLT_MAX;
      vmin[i][j] = FLT_MAX;
      cpk[i][j] = 0u;
    }

  const int r = tid >> 3;   // 0..31
  const int c8 = tid & 7;   // 0..7
  const int kcol = c8 * 4;
  const int rsw = c8 << 3;  // staging row swizzle
  const int rA0 = (r + 0) ^ rsw, rA1 = (r + 32) ^ rsw;
  const int rA2 = (r + 64) ^ rsw, rA3 = (r + 96) ^ rsw;
  const int rW0 = (r + 0) ^ rsw, rW1 = (r + 32) ^ rsw;

  int ga0 = m0 + r;      ga0 = ga0 < M ? ga0 : M - 1;
  int ga1 = m0 + r + 32; ga1 = ga1 < M ? ga1 : M - 1;
  int ga2 = m0 + r + 64; ga2 = ga2 < M ? ga2 : M - 1;
  int ga3 = m0 + r + 96; ga3 = ga3 < M ? ga3 : M - 1;
  int gw0 = n0 + r;      gw0 = gw0 < N ? gw0 : N - 1;
  int gw1 = n0 + r + 32; gw1 = gw1 < N ? gw1 : N - 1;
  const float* pA0 = A + (size_t)ga0 * K + kcol;
  const float* pA1 = A + (size_t)ga1 * K + kcol;
  const float* pA2 = A + (size_t)ga2 * K + kcol;
  const float* pA3 = A + (size_t)ga3 * K + kcol;
  const float* pW0 = W + (size_t)gw0 * K + kcol;
  const float* pW1 = W + (size_t)gw1 * K + kcol;

  const int nchunk = K / BK;

  // prologue prefetch: chunk 0
  f32x4 fa0 = *(const f32x4*)pA0;
  f32x4 fa1 = *(const f32x4*)pA1;
  f32x4 fa2 = *(const f32x4*)pA2;
  f32x4 fa3 = *(const f32x4*)pA3;
  f32x4 fw0 = *(const f32x4*)pW0;
  f32x4 fw1 = *(const f32x4*)pW1;

  for (int ch = 0; ch < nchunk; ++ch) {
    // stage prefetched regs -> LDS (transpose, swizzled rows: 2-way banks)
    Als[kcol + 0][rA0] = fa0.x; Als[kcol + 1][rA0] = fa0.y;
    Als[kcol + 2][rA0] = fa0.z; Als[kcol + 3][rA0] = fa0.w;
    Als[kcol + 0][rA1] = fa1.x; Als[kcol + 1][rA1] = fa1.y;
    Als[kcol + 2][rA1] = fa1.z; Als[kcol + 3][rA1] = fa1.w;
    Als[kcol + 0][rA2] = fa2.x; Als[kcol + 1][rA2] = fa2.y;
    Als[kcol + 2][rA2] = fa2.z; Als[kcol + 3][rA2] = fa2.w;
    Als[kcol + 0][rA3] = fa3.x; Als[kcol + 1][rA3] = fa3.y;
    Als[kcol + 2][rA3] = fa3.z; Als[kcol + 3][rA3] = fa3.w;
    Wls[kcol + 0][rW0] = fw0.x; Wls[kcol + 1][rW0] = fw0.y;
    Wls[kcol + 2][rW0] = fw0.z; Wls[kcol + 3][rW0] = fw0.w;
    Wls[kcol + 0][rW1] = fw1.x; Wls[kcol + 1][rW1] = fw1.y;
    Wls[kcol + 2][rW1] = fw1.z; Wls[kcol + 3][rW1] = fw1.w;
    __syncthreads();

    if (ch + 1 < nchunk) {
      const int koff = (ch + 1) * BK;
      fa0 = *(const f32x4*)(pA0 + koff);
      fa1 = *(const f32x4*)(pA1 + koff);
      fa2 = *(const f32x4*)(pA2 + koff);
      fa3 = *(const f32x4*)(pA3 + koff);
      fw0 = *(const f32x4*)(pW0 + koff);
      fw1 = *(const f32x4*)(pW1 + koff);
    }

    float tmax[8][4], tmin[8][4];
#pragma unroll
    for (int i = 0; i < 8; ++i)
#pragma unroll
      for (int j = 0; j < 4; ++j) { tmax[i][j] = -FLT_MAX; tmin[i][j] = FLT_MAX; }

#pragma unroll
    for (int k = 0; k < BK; k += 2) {
      const int swz = (k >> 2) << 3;
      const int ab = (ty * 8) ^ swz;
      const int wb = (tx * 4) ^ swz;
      const f32x4 a0l = *(const f32x4*)(&Als[k][ab]);        // rows 0-3
      const f32x4 a0h = *(const f32x4*)(&Als[k][ab + 4]);    // rows 4-7
      const f32x4 a1l = *(const f32x4*)(&Als[k + 1][ab]);
      const f32x4 a1h = *(const f32x4*)(&Als[k + 1][ab + 4]);
      const f32x4 w0 = *(const f32x4*)(&Wls[k][wb]);
      const f32x4 w1 = *(const f32x4*)(&Wls[k + 1][wb]);
      const f32x2 w0lo = w0.xy, w0hi = w0.zw;
      const f32x2 w1lo = w1.xy, w1hi = w1.zw;

#define ACC2(I0, A0P, A1P, J, FN, WP0, WP1)                          \
      { const f32x2 q0 = FN(A0P, WP0);                               \
        const f32x2 q1 = FN(A1P, WP1);                               \
        tmax[I0][J] = fmaxf(tmax[I0][J], fmaxf(q0.x, q1.x));         \
        tmin[I0][J] = fminf(tmin[I0][J], fminf(q0.x, q1.x));         \
        tmax[I0 + 1][J] = fmaxf(tmax[I0 + 1][J], fmaxf(q0.y, q1.y)); \
        tmin[I0 + 1][J] = fminf(tmin[I0 + 1][J], fminf(q0.y, q1.y)); }

      ACC2(0, a0l.xy, a1l.xy, 0, pk_mul_blo, w0lo, w1lo)
      ACC2(2, a0l.zw, a1l.zw, 0, pk_mul_blo, w0lo, w1lo)
      ACC2(4, a0h.xy, a1h.xy, 0, pk_mul_blo, w0lo, w1lo)
      ACC2(6, a0h.zw, a1h.zw, 0, pk_mul_blo, w0lo, w1lo)
      ACC2(0, a0l.xy, a1l.xy, 1, pk_mul_bhi, w0lo, w1lo)
      ACC2(2, a0l.zw, a1l.zw, 1, pk_mul_bhi, w0lo, w1lo)
      ACC2(4, a0h.xy, a1h.xy, 1, pk_mul_bhi, w0lo, w1lo)
      ACC2(6, a0h.zw, a1h.zw, 1, pk_mul_bhi, w0lo, w1lo)
      ACC2(0, a0l.xy, a1l.xy, 2, pk_mul_blo, w0hi, w1hi)
      ACC2(2, a0l.zw, a1l.zw, 2, pk_mul_blo, w0hi, w1hi)
      ACC2(4, a0h.xy, a1h.xy, 2, pk_mul_blo, w0hi, w1hi)
      ACC2(6, a0h.zw, a1h.zw, 2, pk_mul_blo, w0hi, w1hi)
      ACC2(0, a0l.xy, a1l.xy, 3, pk_mul_bhi, w0hi, w1hi)
      ACC2(2, a0l.zw, a1l.zw, 3, pk_mul_bhi, w0hi, w1hi)
      ACC2(4, a0h.xy, a1h.xy, 3, pk_mul_bhi, w0hi, w1hi)
      ACC2(6, a0h.zw, a1h.zw, 3, pk_mul_bhi, w0hi, w1hi)
#undef ACC2
    }

#pragma unroll
    for (int i = 0; i < 8; ++i)
#pragma unroll
      for (int j = 0; j < 4; ++j) {
        if (tmax[i][j] > vmax[i][j]) {
          vmax[i][j] = tmax[i][j];
          cpk[i][j] = (cpk[i][j] & 0xFF00u) | (unsigned)ch;
        }
        if (tmin[i][j] < vmin[i][j]) {
          vmin[i][j] = tmin[i][j];
          cpk[i][j] = (cpk[i][j] & 0x00FFu) | ((unsigned)ch << 8);
        }
      }
    __syncthreads();
  }

  // ---- rescan prefetch issued early (hides under epilogue + bucketing) ----
  const int row2 = tid >> 1;        // 0..127 (A rescan row)
  const int h2 = (tid & 1) * 16;    // col offset (floats)
  const int rw2 = tid >> 2;         // 0..63 (W rescan row)
  const int q8 = (tid & 3) * 8;
  int gmr = m0 + row2; gmr = gmr < M ? gmr : M - 1;
  int gnr = n0 + rw2;  gnr = gnr < N ? gnr : N - 1;
  const float* pAr = A + (size_t)gmr * K + h2;
  const float* pWr = W + (size_t)gnr * K + q8;
  f32x4 ra0 = *(const f32x4*)(pAr);
  f32x4 ra1 = *(const f32x4*)(pAr + 4);
  f32x4 ra2 = *(const f32x4*)(pAr + 8);
  f32x4 ra3 = *(const f32x4*)(pAr + 12);
  f32x4 rb0 = *(const f32x4*)(pWr);
  f32x4 rb1 = *(const f32x4*)(pWr + 4);

  // ---- value output (no target parking) ----
  const int gn = n0 + tx * 4;
  f32x4 bv = {0.f, 0.f, 0.f, 0.f};
  if (gn + 3 < N) bv = *(const f32x4*)(bias + gn);
#pragma unroll
  for (int i = 0; i < 8; ++i) {
    const int gm = m0 + ty * 8 + i;
    if (gm < M && gn + 3 < N) {
      const f32x4 vx = {vmax[i][0], vmax[i][1], vmax[i][2], vmax[i][3]};
      const f32x4 vn = {vmin[i][0], vmin[i][1], vmin[i][2], vmin[i][3]};
      *(f32x4*)(out_v + (size_t)gm * N + gn) = vx + vn + bv;
    }
  }

  // ---- bucket entries by chunk (side rides in the entry, bit 13) ----
  if (tid < NCHUNK) cnt[tid] = 0;
  __syncthreads();
#pragma unroll
  for (int i = 0; i < 8; ++i)
#pragma unroll
    for (int j = 0; j < 4; ++j) {
      atomicAdd(&cnt[cpk[i][j] & 255u], 1u);
      atomicAdd(&cnt[cpk[i][j] >> 8], 1u);
    }
  __syncthreads();
  if (tid == 0) {
    unsigned s = 0;
    for (int b = 0; b < NCHUNK; ++b) { off[b] = s; s += cnt[b]; }
    off[NCHUNK] = s;
  }
  __syncthreads();
  if (tid < NCHUNK) cnt[tid] = off[tid];
  __syncthreads();
#pragma unroll
  for (int i = 0; i < 8; ++i)
#pragma unroll
    for (int j = 0; j < 4; ++j) {
      const unsigned enc = (unsigned)((ty * 8 + i) * 64 + (tx * 4 + j));
      unsigned p1 = atomicAdd(&cnt[cpk[i][j] & 255u], 1u);
      ents[p1] = (unsigned short)enc;                 // side 0 (max)
      unsigned p2 = atomicAdd(&cnt[cpk[i][j] >> 8], 1u);
      ents[p2] = (unsigned short)(enc | 0x2000u);     // side 1 (min)
    }

  // ---- per-chunk rescan: recompute in-chunk argmax (first occurrence) ----
  for (int ch = 0; ch < nchunk; ++ch) {
    const int kk = ch * BK;
    __syncthreads();  // prior readers (and bucketing/epilogue) done
    *(f32x4*)(&As2[row2][h2 + 0]) = ra0;
    *(f32x4*)(&As2[row2][h2 + 4]) = ra1;
    *(f32x4*)(&As2[row2][h2 + 8]) = ra2;
    *(f32x4*)(&As2[row2][h2 + 12]) = ra3;
    *(f32x4*)(&Ws2[rw2][q8 + 0]) = rb0;
    *(f32x4*)(&Ws2[rw2][q8 + 4]) = rb1;
    if (ch + 1 < nchunk) {
      const int koff = (ch + 1) * BK;
      ra0 = *(const f32x4*)(pAr + koff);
      ra1 = *(const f32x4*)(pAr + koff + 4);
      ra2 = *(const f32x4*)(pAr + koff + 8);
      ra3 = *(const f32x4*)(pAr + koff + 12);
      rb0 = *(const f32x4*)(pWr + koff);
      rb1 = *(const f32x4*)(pWr + koff + 4);
    }
    __syncthreads();

    const int lo = off[ch], hi = off[ch + 1];
    for (int e = lo + tid; e < hi; e += 256) {
      const int enc = ents[e];
      const unsigned smask = (enc & 0x2000) ? 0x80000000u : 0u;
      const int ml = (enc >> 6) & 127;
      const int nl = enc & 63;
      float cur = -FLT_MAX;
      int pos = 0;
#pragma unroll
      for (int g = 0; g < 8; ++g) {  // ascending k, strict > = first occur.
        const f32x4 a4 = *(const f32x4*)(&As2[ml][g * 4]);
        const f32x4 w4 = *(const f32x4*)(&Ws2[nl][g * 4]);
        const float wx = __uint_as_float(__float_as_uint(w4.x) ^ smask);
        const float wy = __uint_as_float(__float_as_uint(w4.y) ^ smask);
        const float wz = __uint_as_float(__float_as_uint(w4.z) ^ smask);
        const float ww = __uint_as_float(__float_as_uint(w4.w) ^ smask);
        float p;
        p = a4.x * wx; if (p > cur) { cur = p; pos = g * 4 + 0; }
        p = a4.y * wy; if (p > cur) { cur = p; pos = g * 4 + 1; }
        p = a4.z * wz; if (p > cur) { cur = p; pos = g * 4 + 2; }
        p = a4.w * ww; if (p > cur) { cur = p; pos = g * 4 + 3; }
      }
      const int gm = m0 + ml, gnn = n0 + nl;
      if (gm < M && gnn < N) {
        float* outp = (enc & 0x2000) ? out_an : out_ax;
        outp[(size_t)gm * N + gnn] = (float)(kk + pos);
      }
    }
  }
}

extern "C" void kernel_launch(void* const* d_in, const int* in_sizes, int n_in,
                              void* d_out, int out_size, void* d_ws, size_t ws_size,
                              hipStream_t stream) {
  const float* A = (const float*)d_in[0];     // [M, K] fp32
  const float* W = (const float*)d_in[1];     // [N, K] fp32
  const float* bias = (const float*)d_in[2];  // [N]    fp32
  const int N = in_sizes[2];
  const int K = in_sizes[1] / N;
  const int M = in_sizes[0] / K;
  float* out_v = (float*)d_out;
  float* out_ax = out_v + (size_t)M * N;
  float* out_an = out_v + 2 * (size_t)M * N;
  dim3 grid((N + BN - 1) / BN, (M + BM - 1) / BM);
  mam_fused<<<grid, dim3(256), 0, stream>>>(A, W, bias, out_v, out_ax, out_an,
                                            M, N, K);
}

// Round 3
// 1092.510 us; speedup vs baseline: 1.3597x; 1.3597x over previous
//
#include <hip/hip_runtime.h>
#include <float.h>

// MAM dense, fused. C[m,n] = max_k(A[m,k]*W[n,k]) + min_k + bias[n] + arg
// indices (numpy first-occurrence).
//
// R3: RESCAN ELIMINATED. Main pass tracks the 4-k WINDOW of last strict
// improvement: nv = max3(v, max3(p0,p1,p2), p3); (nv != v) -> pos = wnd.
// Ties keep the earlier window (= first occurrence across windows); the
// within-window first occurrence is resolved in a tiny epilogue that re-reads
// the 4 A / 4 W values per output from global (L2-hot) and recomputes the 4
// products (bitwise-identical IEEE muls; R2 passing proved pk_mul == scalar
// mul bitwise). This deletes: ents (32KB LDS), bucketing atomics, the
// 32-iteration rescan loop with its random-row b128 LDS gathers (~200us of
// LDS-pipe time + the bulk of 7.2e7 bank conflicts in R0).
//
// R2 lesson: 8x4 tile spilled (VGPR 128 < ~200 live) -> 1.6GB scratch
// traffic. R3 stays at 4x4; accumulator state is now vmax/vmin(32) +
// pmax/pmin(32) = 64 regs, LESS than R0's 96.
//
//  - pk_mul (VOP3P packed fp32, op_sel broadcast of W scalar) kept.
//  - XOR-swizzled transpose staging (row ^ (c8<<3)), reads XOR group base by
//    (k>>2)<<3 -- window-aligned, so a 4-k quad shares one swizzle.
//  - global->reg prefetch software pipeline kept.
// LDS: Als[32][68] + Wls[32][68] = 17408B -> ~3 blocks/CU (VGPR-bound).

typedef float f32x2 __attribute__((ext_vector_type(2)));
typedef float f32x4 __attribute__((ext_vector_type(4)));

#define BM 64
#define BN 64
#define BK 32
#define LDP 68  // staging [BK][LDP], transpose layout, +4 pad

// D.lo = S0.lo * S1.lo ; D.hi = S0.hi * S1.lo   (broadcast S1 low half)
__device__ __forceinline__ f32x2 pk_mul_blo(f32x2 a, f32x2 w) {
  f32x2 d;
  asm("v_pk_mul_f32 %0, %1, %2 op_sel:[0,0] op_sel_hi:[1,0]"
      : "=v"(d) : "v"(a), "v"(w));
  return d;
}
// D.lo = S0.lo * S1.hi ; D.hi = S0.hi * S1.hi   (broadcast S1 high half)
__device__ __forceinline__ f32x2 pk_mul_bhi(f32x2 a, f32x2 w) {
  f32x2 d;
  asm("v_pk_mul_f32 %0, %1, %2 op_sel:[0,1] op_sel_hi:[1,1]"
      : "=v"(d) : "v"(a), "v"(w));
  return d;
}

__global__ __launch_bounds__(256)
void mam_fused(const float* __restrict__ A, const float* __restrict__ W,
               const float* __restrict__ bias,
               float* __restrict__ out_v, float* __restrict__ out_ax,
               float* __restrict__ out_an, int M, int N, int K) {
  __shared__ __align__(16) float Als[BK][LDP];
  __shared__ __align__(16) float Wls[BK][LDP];

  const int tid = threadIdx.x;
  const int tx = tid & 15;   // n: 4 cols
  const int ty = tid >> 4;   // m: 4 rows
  const int m0 = blockIdx.y * BM;
  const int n0 = blockIdx.x * BN;
  const int ty4 = ty * 4, tx4 = tx * 4;

  float vmax[4][4], vmin[4][4];
  int pmax[4][4], pmin[4][4];  // 4-k window index of first occurrence
#pragma unroll
  for (int i = 0; i < 4; ++i)
#pragma unroll
    for (int j = 0; j < 4; ++j) {
      vmax[i][j] = -FLT_MAX;
      vmin[i][j] = FLT_MAX;
      pmax[i][j] = 0;
      pmin[i][j] = 0;
    }

  const int r = tid >> 3;   // 0..31
  const int c8 = tid & 7;   // 0..7
  const int kcol = c8 * 4;
  const int rsw = c8 << 3;  // staging row swizzle
  const int rA0 = (r + 0) ^ rsw, rA1 = (r + 32) ^ rsw;

  int ga0 = m0 + r;      ga0 = ga0 < M ? ga0 : M - 1;
  int ga1 = m0 + r + 32; ga1 = ga1 < M ? ga1 : M - 1;
  int gw0 = n0 + r;      gw0 = gw0 < N ? gw0 : N - 1;
  int gw1 = n0 + r + 32; gw1 = gw1 < N ? gw1 : N - 1;
  const float* pA0 = A + (size_t)ga0 * K + kcol;
  const float* pA1 = A + (size_t)ga1 * K + kcol;
  const float* pW0 = W + (size_t)gw0 * K + kcol;
  const float* pW1 = W + (size_t)gw1 * K + kcol;

  const int nchunk = K / BK;

  // prologue prefetch: chunk 0
  f32x4 fa0 = *(const f32x4*)pA0;
  f32x4 fa1 = *(const f32x4*)pA1;
  f32x4 fw0 = *(const f32x4*)pW0;
  f32x4 fw1 = *(const f32x4*)pW1;

  for (int ch = 0; ch < nchunk; ++ch) {
    // stage prefetched regs -> LDS (transpose, swizzled rows)
    Als[kcol + 0][rA0] = fa0.x; Als[kcol + 1][rA0] = fa0.y;
    Als[kcol + 2][rA0] = fa0.z; Als[kcol + 3][rA0] = fa0.w;
    Als[kcol + 0][rA1] = fa1.x; Als[kcol + 1][rA1] = fa1.y;
    Als[kcol + 2][rA1] = fa1.z; Als[kcol + 3][rA1] = fa1.w;
    Wls[kcol + 0][rA0] = fw0.x; Wls[kcol + 1][rA0] = fw0.y;
    Wls[kcol + 2][rA0] = fw0.z; Wls[kcol + 3][rA0] = fw0.w;
    Wls[kcol + 0][rA1] = fw1.x; Wls[kcol + 1][rA1] = fw1.y;
    Wls[kcol + 2][rA1] = fw1.z; Wls[kcol + 3][rA1] = fw1.w;
    __syncthreads();

    if (ch + 1 < nchunk) {
      const int koff = (ch + 1) * BK;
      fa0 = *(const f32x4*)(pA0 + koff);
      fa1 = *(const f32x4*)(pA1 + koff);
      fw0 = *(const f32x4*)(pW0 + koff);
      fw1 = *(const f32x4*)(pW1 + koff);
    }

#pragma unroll
    for (int k = 0; k < BK; k += 4) {
      const int wnd = ch * (BK / 4) + (k >> 2);  // global 4-k window index
      const int swz = (k >> 2) << 3;
      const int ab = ty4 ^ swz;
      const int wb = tx4 ^ swz;
      const f32x4 a0 = *(const f32x4*)(&Als[k + 0][ab]);
      const f32x4 a1 = *(const f32x4*)(&Als[k + 1][ab]);
      const f32x4 a2 = *(const f32x4*)(&Als[k + 2][ab]);
      const f32x4 a3 = *(const f32x4*)(&Als[k + 3][ab]);
      const f32x4 w0 = *(const f32x4*)(&Wls[k + 0][wb]);
      const f32x4 w1 = *(const f32x4*)(&Wls[k + 1][wb]);
      const f32x4 w2 = *(const f32x4*)(&Wls[k + 2][wb]);
      const f32x4 w3 = *(const f32x4*)(&Wls[k + 3][wb]);

      // window-tracked accumulate: 2x max3 + cmp + csel per side per output.
#define TRK(I, J, P0, P1, P2, P3)                                      \
      { const float _t = fmaxf(fmaxf((P0), (P1)), (P2));               \
        const float _n = fmaxf(fmaxf(vmax[I][J], _t), (P3));           \
        pmax[I][J] = (_n != vmax[I][J]) ? wnd : pmax[I][J];            \
        vmax[I][J] = _n;                                               \
        const float _u = fminf(fminf((P0), (P1)), (P2));               \
        const float _m = fminf(fminf(vmin[I][J], _u), (P3));           \
        pmin[I][J] = (_m != vmin[I][J]) ? wnd : pmin[I][J];            \
        vmin[I][J] = _m; }

#pragma unroll
      for (int jh = 0; jh < 2; ++jh) {
        const f32x2 u0 = jh ? w0.zw : w0.xy;
        const f32x2 u1 = jh ? w1.zw : w1.xy;
        const f32x2 u2 = jh ? w2.zw : w2.xy;
        const f32x2 u3 = jh ? w3.zw : w3.xy;
        {  // j = 2*jh : broadcast low half of the W pair
          const int j = 2 * jh;
          f32x2 q0 = pk_mul_blo(a0.xy, u0), q1 = pk_mul_blo(a1.xy, u1);
          f32x2 q2 = pk_mul_blo(a2.xy, u2), q3 = pk_mul_blo(a3.xy, u3);
          TRK(0, j, q0.x, q1.x, q2.x, q3.x)
          TRK(1, j, q0.y, q1.y, q2.y, q3.y)
          q0 = pk_mul_blo(a0.zw, u0); q1 = pk_mul_blo(a1.zw, u1);
          q2 = pk_mul_blo(a2.zw, u2); q3 = pk_mul_blo(a3.zw, u3);
          TRK(2, j, q0.x, q1.x, q2.x, q3.x)
          TRK(3, j, q0.y, q1.y, q2.y, q3.y)
        }
        {  // j = 2*jh+1 : broadcast high half of the W pair
          const int j = 2 * jh + 1;
          f32x2 q0 = pk_mul_bhi(a0.xy, u0), q1 = pk_mul_bhi(a1.xy, u1);
          f32x2 q2 = pk_mul_bhi(a2.xy, u2), q3 = pk_mul_bhi(a3.xy, u3);
          TRK(0, j, q0.x, q1.x, q2.x, q3.x)
          TRK(1, j, q0.y, q1.y, q2.y, q3.y)
          q0 = pk_mul_bhi(a0.zw, u0); q1 = pk_mul_bhi(a1.zw, u1);
          q2 = pk_mul_bhi(a2.zw, u2); q3 = pk_mul_bhi(a3.zw, u3);
          TRK(2, j, q0.x, q1.x, q2.x, q3.x)
          TRK(3, j, q0.y, q1.y, q2.y, q3.y)
        }
      }
#undef TRK
    }
    __syncthreads();
  }

  // ---- epilogue: values + within-window argmax from global (L2-hot) ----
  const int gnb = n0 + tx4;
  f32x4 bv = {0.f, 0.f, 0.f, 0.f};
  if (gnb + 3 < N) bv = *(const f32x4*)(bias + gnb);

#pragma unroll
  for (int i = 0; i < 4; ++i) {
    const int gm = m0 + ty4 + i;
    if (gm >= M || gnb + 3 >= N) continue;
    const size_t base = (size_t)gm * N + gnb;

    const f32x4 vx = {vmax[i][0], vmax[i][1], vmax[i][2], vmax[i][3]};
    const f32x4 vn = {vmin[i][0], vmin[i][1], vmin[i][2], vmin[i][3]};
    *(f32x4*)(out_v + base) = vx + vn + bv;

    f32x4 ax, an;
#pragma unroll
    for (int j = 0; j < 4; ++j) {
      const int gn = gnb + j;
      {  // max side: first k in window with strict-> scan ascending
        const int kb = pmax[i][j] * 4;
        const f32x4 a = *(const f32x4*)(A + (size_t)gm * K + kb);
        const f32x4 w = *(const f32x4*)(W + (size_t)gn * K + kb);
        float cur = -FLT_MAX; int pos = 0; float p;
        p = a.x * w.x; if (p > cur) { cur = p; pos = 0; }
        p = a.y * w.y; if (p > cur) { cur = p; pos = 1; }
        p = a.z * w.z; if (p > cur) { cur = p; pos = 2; }
        p = a.w * w.w; if (p > cur) { cur = p; pos = 3; }
        ax[j] = (float)(kb + pos);
      }
      {  // min side
        const int kb = pmin[i][j] * 4;
        const f32x4 a = *(const f32x4*)(A + (size_t)gm * K + kb);
        const f32x4 w = *(const f32x4*)(W + (size_t)gn * K + kb);
        float cur = FLT_MAX; int pos = 0; float p;
        p = a.x * w.x; if (p < cur) { cur = p; pos = 0; }
        p = a.y * w.y; if (p < cur) { cur = p; pos = 1; }
        p = a.z * w.z; if (p < cur) { cur = p; pos = 2; }
        p = a.w * w.w; if (p < cur) { cur = p; pos = 3; }
        an[j] = (float)(kb + pos);
      }
    }
    *(f32x4*)(out_ax + base) = ax;
    *(f32x4*)(out_an + base) = an;
  }
}

extern "C" void kernel_launch(void* const* d_in, const int* in_sizes, int n_in,
                              void* d_out, int out_size, void* d_ws, size_t ws_size,
                              hipStream_t stream) {
  const float* A = (const float*)d_in[0];     // [M, K] fp32
  const float* W = (const float*)d_in[1];     // [N, K] fp32
  const float* bias = (const float*)d_in[2];  // [N]    fp32
  const int N = in_sizes[2];
  const int K = in_sizes[1] / N;
  const int M = in_sizes[0] / K;
  float* out_v = (float*)d_out;
  float* out_ax = out_v + (size_t)M * N;
  float* out_an = out_v + 2 * (size_t)M * N;
  dim3 grid((N + BN - 1) / BN, (M + BM - 1) / BM);
  mam_fused<<<grid, dim3(256), 0, stream>>>(A, W, bias, out_v, out_ax, out_an,
                                            M, N, K);
}

// Round 4
// 746.461 us; speedup vs baseline: 1.9900x; 1.4636x over previous
//
#include <hip/hip_runtime.h>
#include <float.h>

// MAM dense, fused. C[m,n] = max_k(A[m,k]*W[n,k]) + min_k + bias[n] + arg
// indices (numpy first-occurrence).
//
// R4: window-tracking algorithm (R3, validated bit-exact) rebuilt for
// residency + LDS efficiency:
//  - LDS row-major [row][32 floats] with XOR-quad swizzle (q ^= row&7),
//    applied on BOTH the DMA source and the read side (involution, rule:
//    both-sides-or-neither). Enables global_load_lds width=16 for A AND W:
//    no prefetch VGPRs, no staging ds_writes, 4 DMA instr/thread/chunk.
//  - Double-buffered (2 x 16KB), ONE barrier per chunk (was 2).
//  - W cols per thread = {tx, tx+16, tx+32, tx+48}: W reads 2-way max.
//  - Products pair along k -> plain elementwise v_pk_mul_f32.
//  - 4-k window tracking: t=max3(p0,p1,p2); n=max3(v,t,p3); (n!=v)->wnd.
//    Ties keep earlier window = first occurrence. Epilogue re-reads the 4
//    A/W values per output/side from global (L3-hot) for within-window
//    first-occurrence. No rescan, no ents, no bucketing.
//  - Address math: bases pre-XORed with swizzle bits; per read ONE v_xor
//    with a compile-time constant (KQ<<4).
// Target: VGPR <= 128 -> 4 waves/SIMD; LDS 32KB -> 4 blocks/CU; 16 waves/CU.

typedef float f32x2 __attribute__((ext_vector_type(2)));
typedef float f32x4 __attribute__((ext_vector_type(4)));

#define BM 64
#define BN 64
#define BK 32

__device__ __forceinline__ f32x2 pk_mul(f32x2 a, f32x2 b) {
  f32x2 d;
  asm("v_pk_mul_f32 %0, %1, %2" : "=v"(d) : "v"(a), "v"(b));
  return d;
}

#define GLOAD16(gp, lp)                                                \
  __builtin_amdgcn_global_load_lds(                                    \
      (const __attribute__((address_space(1))) unsigned int*)(gp),     \
      (__attribute__((address_space(3))) unsigned int*)(lp), 16, 0, 0)

__global__ __launch_bounds__(256, 3)
void mam_fused(const float* __restrict__ A, const float* __restrict__ W,
               const float* __restrict__ bias,
               float* __restrict__ out_v, float* __restrict__ out_ax,
               float* __restrict__ out_an, int M, int N, int K) {
  // [buf][mat][row][word]; mat 0 = A (m-rows), 1 = W (n-rows). 128B rows.
  __shared__ __align__(16) float lds[2][2][64][32];

  const int tid = threadIdx.x;
  const int tx = tid & 15;  // n-group: cols tx, tx+16, tx+32, tx+48
  const int ty = tid >> 4;  // m-group: rows ty*4 .. ty*4+3
  const int m0 = blockIdx.y * BM;
  const int n0 = blockIdx.x * BN;

  // ---- DMA mapping: wave wv, slot t covers quads gq = wv*128 + t*64 + ln ----
  const int wv = tid >> 6;
  const int ln = tid & 63;
  const int gq0 = wv * 128 + ln;          // t=0 quad id
  const int row0 = gq0 >> 3;              // t=1 row = row0 + 8 (same q, csw)
  const int q0 = gq0 & 7;
  const int csw = ((q0 ^ (row0 & 7)) << 2);  // swizzled source col (floats)
  int ga0 = m0 + row0;     ga0 = ga0 < M ? ga0 : M - 1;
  int ga1 = m0 + row0 + 8; ga1 = ga1 < M ? ga1 : M - 1;
  int gw0 = n0 + row0;     gw0 = gw0 < N ? gw0 : N - 1;
  int gw1 = n0 + row0 + 8; gw1 = gw1 < N ? gw1 : N - 1;
  const float* sA0 = A + (size_t)ga0 * K + csw;
  const float* sA1 = A + (size_t)ga1 * K + csw;
  const float* sW0 = W + (size_t)gw0 * K + csw;
  const float* sW1 = W + (size_t)gw1 * K + csw;
  float* const ldsf = &lds[0][0][0][0];
  const int dmaw = wv * 512;  // wave-uniform dest base (floats) within a mat

#define ISSUE(CH, BUF)                                                   \
  {                                                                      \
    const int _kk = (CH)*BK;                                             \
    float* _dA = ldsf + (BUF)*4096 + dmaw;                               \
    float* _dW = _dA + 2048;                                             \
    GLOAD16(sA0 + _kk, _dA);                                             \
    GLOAD16(sA1 + _kk, _dA + 256);                                       \
    GLOAD16(sW0 + _kk, _dW);                                             \
    GLOAD16(sW1 + _kk, _dW + 256);                                       \
  }

  // ---- accumulators ----
  float vmax[4][4], vmin[4][4];
  int pmax[4][4], pmin[4][4];  // 4-k window of first occurrence (0..K/4-1)
#pragma unroll
  for (int i = 0; i < 4; ++i)
#pragma unroll
    for (int j = 0; j < 4; ++j) {
      vmax[i][j] = -FLT_MAX;
      vmin[i][j] = FLT_MAX;
      pmax[i][j] = 0;
      pmin[i][j] = 0;
    }

  // ---- read bases (bytes), swizzle pre-XORed; per read: base ^ (KQ<<4) ----
  const int ab0 = (ty * 4 + 0) * 128 + (((ty * 4 + 0) & 7) << 4);
  const int ab1 = (ty * 4 + 1) * 128 + (((ty * 4 + 1) & 7) << 4);
  const int ab2 = (ty * 4 + 2) * 128 + (((ty * 4 + 2) & 7) << 4);
  const int ab3 = (ty * 4 + 3) * 128 + (((ty * 4 + 3) & 7) << 4);
  const int wsw = (tx & 7) << 4;
  const int wb0 = (tx + 0) * 128 + wsw;
  const int wb1 = (tx + 16) * 128 + wsw;
  const int wb2 = (tx + 32) * 128 + wsw;
  const int wb3 = (tx + 48) * 128 + wsw;

  const int nchunk = K / BK;

#define PROD(I, J, AV, WV)                                              \
  {                                                                     \
    const f32x2 qlo = pk_mul((AV).xy, (WV).xy);                         \
    const f32x2 qhi = pk_mul((AV).zw, (WV).zw);                         \
    const float t = fmaxf(fmaxf(qlo.x, qlo.y), qhi.x);                  \
    const float n = fmaxf(fmaxf(vmax[I][J], t), qhi.y);                 \
    pmax[I][J] = (n != vmax[I][J]) ? wnd : pmax[I][J];                  \
    vmax[I][J] = n;                                                     \
    const float u = fminf(fminf(qlo.x, qlo.y), qhi.x);                  \
    const float m2 = fminf(fminf(vmin[I][J], u), qhi.y);                \
    pmin[I][J] = (m2 != vmin[I][J]) ? wnd : pmin[I][J];                 \
    vmin[I][J] = m2;                                                    \
  }

#define DO4(J, WV) PROD(0, J, a0v, WV) PROD(1, J, a1v, WV) \
                   PROD(2, J, a2v, WV) PROD(3, J, a3v, WV)

#define KSTEP(KQ)                                                       \
  {                                                                     \
    const int wnd = chw + (KQ);                                         \
    const f32x4 a0v = *(const f32x4*)(Abc + (ab0 ^ ((KQ) << 4)));       \
    const f32x4 a1v = *(const f32x4*)(Abc + (ab1 ^ ((KQ) << 4)));       \
    const f32x4 a2v = *(const f32x4*)(Abc + (ab2 ^ ((KQ) << 4)));       \
    const f32x4 a3v = *(const f32x4*)(Abc + (ab3 ^ ((KQ) << 4)));       \
    { const f32x4 w0v = *(const f32x4*)(Wbc + (wb0 ^ ((KQ) << 4)));     \
      DO4(0, w0v) }                                                     \
    { const f32x4 w1v = *(const f32x4*)(Wbc + (wb1 ^ ((KQ) << 4)));     \
      DO4(1, w1v) }                                                     \
    { const f32x4 w2v = *(const f32x4*)(Wbc + (wb2 ^ ((KQ) << 4)));     \
      DO4(2, w2v) }                                                     \
    { const f32x4 w3v = *(const f32x4*)(Wbc + (wb3 ^ ((KQ) << 4)));     \
      DO4(3, w3v) }                                                     \
  }

  // ---- main loop: DMA double-buffered, one barrier per chunk ----
  ISSUE(0, 0)
  __syncthreads();  // drains vmcnt: chunk 0 resident
  int buf = 0;
  for (int ch = 0; ch < nchunk; ++ch) {
    if (ch + 1 < nchunk) ISSUE(ch + 1, buf ^ 1)
    const char* Abc = (const char*)(ldsf + buf * 4096);
    const char* Wbc = Abc + 8192;
    const int chw = ch * 8;
    KSTEP(0) KSTEP(1) KSTEP(2) KSTEP(3)
    KSTEP(4) KSTEP(5) KSTEP(6) KSTEP(7)
    __syncthreads();  // readers done + next chunk's DMA drained
    buf ^= 1;
  }

  // ---- epilogue: values + within-window argmax from global (L3-hot) ----
#pragma unroll
  for (int i = 0; i < 4; ++i) {
    const int gm = m0 + ty * 4 + i;
    if (gm >= M) continue;
    const size_t arow = (size_t)gm * K;
#pragma unroll
    for (int j = 0; j < 4; ++j) {
      const int gn = n0 + tx + 16 * j;
      if (gn >= N) continue;
      const size_t base = (size_t)gm * N + gn;
      out_v[base] = vmax[i][j] + vmin[i][j] + bias[gn];
      {  // max side
        const int kb = pmax[i][j] * 4;
        const f32x4 a = *(const f32x4*)(A + arow + kb);
        const f32x4 w = *(const f32x4*)(W + (size_t)gn * K + kb);
        float cur = -FLT_MAX; int pos = 0; float p;
        p = a.x * w.x; if (p > cur) { cur = p; pos = 0; }
        p = a.y * w.y; if (p > cur) { cur = p; pos = 1; }
        p = a.z * w.z; if (p > cur) { cur = p; pos = 2; }
        p = a.w * w.w; if (p > cur) { cur = p; pos = 3; }
        out_ax[base] = (float)(kb + pos);
      }
      {  // min side
        const int kb = pmin[i][j] * 4;
        const f32x4 a = *(const f32x4*)(A + arow + kb);
        const f32x4 w = *(const f32x4*)(W + (size_t)gn * K + kb);
        float cur = FLT_MAX; int pos = 0; float p;
        p = a.x * w.x; if (p < cur) { cur = p; pos = 0; }
        p = a.y * w.y; if (p < cur) { cur = p; pos = 1; }
        p = a.z * w.z; if (p < cur) { cur = p; pos = 2; }
        p = a.w * w.w; if (p < cur) { cur = p; pos = 3; }
        out_an[base] = (float)(kb + pos);
      }
    }
  }
}

extern "C" void kernel_launch(void* const* d_in, const int* in_sizes, int n_in,
                              void* d_out, int out_size, void* d_ws, size_t ws_size,
                              hipStream_t stream) {
  const float* A = (const float*)d_in[0];     // [M, K] fp32
  const float* W = (const float*)d_in[1];     // [N, K] fp32
  const float* bias = (const float*)d_in[2];  // [N]    fp32
  const int N = in_sizes[2];
  const int K = in_sizes[1] / N;
  const int M = in_sizes[0] / K;
  float* out_v = (float*)d_out;
  float* out_ax = out_v + (size_t)M * N;
  float* out_an = out_v + 2 * (size_t)M * N;
  dim3 grid((N + BN - 1) / BN, (M + BM - 1) / BM);
  mam_fused<<<grid, dim3(256), 0, stream>>>(A, W, bias, out_v, out_ax, out_an,
                                            M, N, K);
}

// Round 5
// 675.679 us; speedup vs baseline: 2.1985x; 1.1048x over previous
//
#include <hip/hip_runtime.h>
#include <float.h>

// MAM dense, fused. C[m,n] = max_k(A[m,k]*W[n,k]) + min_k + bias[n] + arg
// indices (numpy first-occurrence).
//
// R5 (on top of R4's win: 912 -> 741 us, VALU-bound at 87% VALUBusy):
//  - Window P=8 (was 4): chain accumulation c = max3(c, q.x, q.y) -- one
//    max3 per pk_mul per side. Tracking (cmp+csel) amortized 2x: 2.5 ->
//    2.0 VALU inst/product. c/d are temps within one 8-k step (no extra
//    live registers -- the R2 spill lesson).
//  - QUAD-MAJOR LDS layout [buf][mat][quad][row][4f]: every ds_read address
//    is base + compile-time immediate (zero address VALU, was 16 XOR/KSTEP);
//    all reads <=2-way bank conflicts (free); no swizzle anywhere.
//    DMA dest stays linear (base + 16*lane, rule 21); source becomes
//    row-per-lane (64 rows x 16B, 4KB stride) -- L2 dedups the 64B lines
//    since sibling waves fetch the neighboring quads in the same phase.
//  - max3/min3 forced via inline asm v_max3_f32/v_min3_f32 (T17: clang
//    only MAY fuse fmaxf chains).
//  - Epilogue: per output/side re-read the winning 8-k window (2 f32x4 from
//    A + 2 from W, L2/L3-hot) and ascending-scan for first occurrence.
//    Products bitwise-match the main pass (plain mul == pk_mul, proven
//    R3/R4 passing).
// LDS 32KB (2 bufs x [A 8KB + W 8KB]); target VGPR ~128.

typedef float f32x2 __attribute__((ext_vector_type(2)));
typedef float f32x4 __attribute__((ext_vector_type(4)));

#define BM 64
#define BN 64
#define BK 32

__device__ __forceinline__ f32x2 pk_mul(f32x2 a, f32x2 b) {
  f32x2 d;
  asm("v_pk_mul_f32 %0, %1, %2" : "=v"(d) : "v"(a), "v"(b));
  return d;
}
__device__ __forceinline__ float vmax3(float a, float b, float c) {
  float d;
  asm("v_max3_f32 %0, %1, %2, %3" : "=v"(d) : "v"(a), "v"(b), "v"(c));
  return d;
}
__device__ __forceinline__ float vmin3(float a, float b, float c) {
  float d;
  asm("v_min3_f32 %0, %1, %2, %3" : "=v"(d) : "v"(a), "v"(b), "v"(c));
  return d;
}

#define GLOAD16(gp, lp)                                                \
  __builtin_amdgcn_global_load_lds(                                    \
      (const __attribute__((address_space(1))) unsigned int*)(gp),     \
      (__attribute__((address_space(3))) unsigned int*)(lp), 16, 0, 0)

__global__ __launch_bounds__(256, 3)
void mam_fused(const float* __restrict__ A, const float* __restrict__ W,
               const float* __restrict__ bias,
               float* __restrict__ out_v, float* __restrict__ out_ax,
               float* __restrict__ out_an, int M, int N, int K) {
  // [buf:2][mat:2 (A,W)][quad:8][row:64][4 floats] = 32768 B
  __shared__ __align__(16) unsigned char pool[32768];

  const int tid = threadIdx.x;
  const int tx = tid & 15;  // n-group: cols tx, tx+16, tx+32, tx+48
  const int ty = tid >> 4;  // m-group: rows ty*4 .. ty*4+3
  const int m0 = blockIdx.y * BM;
  const int n0 = blockIdx.x * BN;

  // ---- DMA mapping: lane ln = row, wave wv covers quads 2wv, 2wv+1 ----
  const int wv = tid >> 6;
  const int ln = tid & 63;
  int gra = m0 + ln; gra = gra < M ? gra : M - 1;
  int grw = n0 + ln; grw = grw < N ? grw : N - 1;
  const float* srcA = A + (size_t)gra * K + wv * 8;
  const float* srcW = W + (size_t)grw * K + wv * 8;
  const unsigned dmabase = (unsigned)wv * 2048u;

#define ISSUE(CH, BUF)                                                 \
  {                                                                    \
    const float* _sa = srcA + (CH)*BK;                                 \
    const float* _sw = srcW + (CH)*BK;                                 \
    unsigned char* _d = pool + (BUF)*16384u + dmabase;                 \
    GLOAD16(_sa, _d);                                                  \
    GLOAD16(_sa + 4, _d + 1024);                                       \
    GLOAD16(_sw, _d + 8192);                                           \
    GLOAD16(_sw + 4, _d + 9216);                                       \
  }

  // ---- accumulators ----
  float vmax[4][4], vmin[4][4];
  int pmax[4][4], pmin[4][4];  // 8-k window of first occurrence (0..K/8-1)
#pragma unroll
  for (int i = 0; i < 4; ++i)
#pragma unroll
    for (int j = 0; j < 4; ++j) {
      vmax[i][j] = -FLT_MAX;
      vmin[i][j] = FLT_MAX;
      pmax[i][j] = 0;
      pmin[i][j] = 0;
    }

  const int nchunk = K / BK;

  // A read: quad q, row ty*4+i -> byte q*1024 + (ty*4+i)*16
  // W read: quad q, row tx+16j -> byte 8192 + q*1024 + tx*16 + j*256
#define ARD(KQ, I) (*(const f32x4*)(Ab + (KQ)*1024 + (I)*16))
#define WRD(KQ, J) (*(const f32x4*)(Wb + (KQ)*1024 + (J)*256))

#define TRK8(I, J, AV0, AV1, WV0, WV1)                                 \
  {                                                                    \
    const f32x2 q0 = pk_mul((AV0).xy, (WV0).xy);                       \
    const f32x2 q1 = pk_mul((AV0).zw, (WV0).zw);                       \
    float c = vmax3(vmax[I][J], q0.x, q0.y);                           \
    float d = vmin3(vmin[I][J], q0.x, q0.y);                           \
    c = vmax3(c, q1.x, q1.y);                                          \
    d = vmin3(d, q1.x, q1.y);                                          \
    const f32x2 q2 = pk_mul((AV1).xy, (WV1).xy);                       \
    const f32x2 q3 = pk_mul((AV1).zw, (WV1).zw);                       \
    c = vmax3(c, q2.x, q2.y);                                          \
    d = vmin3(d, q2.x, q2.y);                                          \
    c = vmax3(c, q3.x, q3.y);                                          \
    d = vmin3(d, q3.x, q3.y);                                          \
    pmax[I][J] = (c != vmax[I][J]) ? wnd : pmax[I][J];                 \
    vmax[I][J] = c;                                                    \
    pmin[I][J] = (d != vmin[I][J]) ? wnd : pmin[I][J];                 \
    vmin[I][J] = d;                                                    \
  }

  // ---- main loop: DMA double-buffered, one barrier per chunk ----
  ISSUE(0, 0)
  __syncthreads();
  int buf = 0;
  for (int ch = 0; ch < nchunk; ++ch) {
    if (ch + 1 < nchunk) ISSUE(ch + 1, buf ^ 1)
    const unsigned bo = (unsigned)buf * 16384u;
    const unsigned char* Ab = pool + bo + ty * 64;
    const unsigned char* Wb = pool + bo + tx * 16;  // +8192 folded in WRD imm? no: add here
    Wb += 8192;
#pragma unroll
    for (int h = 0; h < 4; ++h) {  // 8-k window: quads 2h, 2h+1
      const int wnd = ch * 4 + h;
      const f32x4 aA0 = ARD(2 * h, 0);
      const f32x4 aA1 = ARD(2 * h, 1);
      const f32x4 aA2 = ARD(2 * h, 2);
      const f32x4 aA3 = ARD(2 * h, 3);
      const f32x4 aB0 = ARD(2 * h + 1, 0);
      const f32x4 aB1 = ARD(2 * h + 1, 1);
      const f32x4 aB2 = ARD(2 * h + 1, 2);
      const f32x4 aB3 = ARD(2 * h + 1, 3);
#pragma unroll
      for (int j = 0; j < 4; ++j) {
        const f32x4 w0 = WRD(2 * h, j);
        const f32x4 w1 = WRD(2 * h + 1, j);
        TRK8(0, j, aA0, aB0, w0, w1)
        TRK8(1, j, aA1, aB1, w0, w1)
        TRK8(2, j, aA2, aB2, w0, w1)
        TRK8(3, j, aA3, aB3, w0, w1)
      }
    }
    __syncthreads();
    buf ^= 1;
  }

  // ---- epilogue: values + within-window argmax from global (L2/L3-hot) ----
#pragma unroll
  for (int i = 0; i < 4; ++i) {
    const int gm = m0 + ty * 4 + i;
    if (gm >= M) continue;
    const size_t arow = (size_t)gm * K;
#pragma unroll
    for (int j = 0; j < 4; ++j) {
      const int gn = n0 + tx + 16 * j;
      if (gn >= N) continue;
      const size_t wrow = (size_t)gn * K;
      const size_t base = (size_t)gm * N + gn;
      out_v[base] = vmax[i][j] + vmin[i][j] + bias[gn];
      {  // max side
        const int kb = pmax[i][j] * 8;
        const f32x4 a0 = *(const f32x4*)(A + arow + kb);
        const f32x4 a1 = *(const f32x4*)(A + arow + kb + 4);
        const f32x4 w0 = *(const f32x4*)(W + wrow + kb);
        const f32x4 w1 = *(const f32x4*)(W + wrow + kb + 4);
        float cur = -FLT_MAX; int pos = 0; float p;
        p = a0.x * w0.x; if (p > cur) { cur = p; pos = 0; }
        p = a0.y * w0.y; if (p > cur) { cur = p; pos = 1; }
        p = a0.z * w0.z; if (p > cur) { cur = p; pos = 2; }
        p = a0.w * w0.w; if (p > cur) { cur = p; pos = 3; }
        p = a1.x * w1.x; if (p > cur) { cur = p; pos = 4; }
        p = a1.y * w1.y; if (p > cur) { cur = p; pos = 5; }
        p = a1.z * w1.z; if (p > cur) { cur = p; pos = 6; }
        p = a1.w * w1.w; if (p > cur) { cur = p; pos = 7; }
        out_ax[base] = (float)(kb + pos);
      }
      {  // min side
        const int kb = pmin[i][j] * 8;
        const f32x4 a0 = *(const f32x4*)(A + arow + kb);
        const f32x4 a1 = *(const f32x4*)(A + arow + kb + 4);
        const f32x4 w0 = *(const f32x4*)(W + wrow + kb);
        const f32x4 w1 = *(const f32x4*)(W + wrow + kb + 4);
        float cur = FLT_MAX; int pos = 0; float p;
        p = a0.x * w0.x; if (p < cur) { cur = p; pos = 0; }
        p = a0.y * w0.y; if (p < cur) { cur = p; pos = 1; }
        p = a0.z * w0.z; if (p < cur) { cur = p; pos = 2; }
        p = a0.w * w0.w; if (p < cur) { cur = p; pos = 3; }
        p = a1.x * w1.x; if (p < cur) { cur = p; pos = 4; }
        p = a1.y * w1.y; if (p < cur) { cur = p; pos = 5; }
        p = a1.z * w1.z; if (p < cur) { cur = p; pos = 6; }
        p = a1.w * w1.w; if (p < cur) { cur = p; pos = 7; }
        out_an[base] = (float)(kb + pos);
      }
    }
  }
}

extern "C" void kernel_launch(void* const* d_in, const int* in_sizes, int n_in,
                              void* d_out, int out_size, void* d_ws, size_t ws_size,
                              hipStream_t stream) {
  const float* A = (const float*)d_in[0];     // [M, K] fp32
  const float* W = (const float*)d_in[1];     // [N, K] fp32
  const float* bias = (const float*)d_in[2];  // [N]    fp32
  const int N = in_sizes[2];
  const int K = in_sizes[1] / N;
  const int M = in_sizes[0] / K;
  float* out_v = (float*)d_out;
  float* out_ax = out_v + (size_t)M * N;
  float* out_an = out_v + 2 * (size_t)M * N;
  dim3 grid((N + BN - 1) / BN, (M + BM - 1) / BM);
  mam_fused<<<grid, dim3(256), 0, stream>>>(A, W, bias, out_v, out_ax, out_an,
                                            M, N, K);
}